// Round 1
// baseline (593.544 us; speedup 1.0000x reference)
//
#include <hip/hip_runtime.h>
#include <hip/hip_bf16.h>
#include <cstdint>

#define INCH 128
#define NHID 256
#define OUTCH 128

// ---------------- threefry2x32 (JAX-compatible) ----------------
__device__ __forceinline__ unsigned rotl32(unsigned x, int d) {
    return (x << d) | (x >> (32 - d));
}

__device__ __forceinline__ void threefry2x32(unsigned k0, unsigned k1,
                                             unsigned x0, unsigned x1,
                                             unsigned& o0, unsigned& o1) {
    unsigned ks2 = k0 ^ k1 ^ 0x1BD11BDAu;
#define TF_R(r) { x0 += x1; x1 = rotl32(x1, (r)); x1 ^= x0; }
    x0 += k0; x1 += k1;
    TF_R(13) TF_R(15) TF_R(26) TF_R(6)
    x0 += k1; x1 += ks2 + 1u;
    TF_R(17) TF_R(29) TF_R(16) TF_R(24)
    x0 += ks2; x1 += k0 + 2u;
    TF_R(13) TF_R(15) TF_R(26) TF_R(6)
    x0 += k0; x1 += k1 + 3u;
    TF_R(17) TF_R(29) TF_R(16) TF_R(24)
    x0 += k1; x1 += ks2 + 4u;
    TF_R(13) TF_R(15) TF_R(26) TF_R(6)
    x0 += ks2; x1 += k0 + 5u;
#undef TF_R
    o0 = x0; o1 = x1;
}

// JAX partitionable threefry, 32-bit draw: counter = flat index j (hi=0, lo=j),
// key = (0, 42); bits = o0 ^ o1. uniform<0.5  <=>  MSB(bits)==0.
__device__ __forceinline__ bool dropout_keep(unsigned j) {
    unsigned o0, o1;
    threefry2x32(0u, 42u, 0u, j, o0, o1);
    return ((o0 ^ o1) & 0x80000000u) == 0u;
}

// ---------------- graph preprocessing ----------------
__global__ void k_init(float* deg, int* cnt, int N) {
    int i = blockIdx.x * blockDim.x + threadIdx.x;
    if (i < N) { deg[i] = 1.0f; cnt[i] = 0; }  // self-loop weight 1
}

__global__ void k_edge_deg_hist(const int* __restrict__ dst, const float* __restrict__ w,
                                float* deg, int* cnt, int E) {
    int e = blockIdx.x * blockDim.x + threadIdx.x;
    if (e < E) {
        int d = dst[e];
        atomicAdd(&deg[d], w[e]);
        atomicAdd(&cnt[d], 1);
    }
}

__global__ void k_dinv(float* deg, int N) {
    int i = blockIdx.x * blockDim.x + threadIdx.x;
    if (i < N) {
        float dg = deg[i];
        deg[i] = (dg > 0.f) ? rsqrtf(dg) : 0.f;
    }
}

__global__ void scan_block(const int* __restrict__ cnt, int* __restrict__ rowptr,
                           int* __restrict__ bsum, int N) {
    __shared__ int s[256];
    int t = threadIdx.x;
    int i = blockIdx.x * 256 + t;
    int v = (i < N) ? cnt[i] : 0;
    s[t] = v;
    __syncthreads();
    for (int off = 1; off < 256; off <<= 1) {
        int tv = (t >= off) ? s[t - off] : 0;
        __syncthreads();
        s[t] += tv;
        __syncthreads();
    }
    if (i < N) rowptr[i] = s[t] - v;          // exclusive within block
    if (t == 255) bsum[blockIdx.x] = s[255];  // block total
}

__global__ void scan_partials(int* bsum, int nb) {
    __shared__ int s[256];
    int t = threadIdx.x;
    int v = (t < nb) ? bsum[t] : 0;
    s[t] = v;
    __syncthreads();
    for (int off = 1; off < 256; off <<= 1) {
        int tv = (t >= off) ? s[t - off] : 0;
        __syncthreads();
        s[t] += tv;
        __syncthreads();
    }
    if (t < nb) bsum[t] = s[t] - v;  // exclusive
}

__global__ void scan_add(int* rowptr, int* cursor, const int* __restrict__ bsum,
                         int N, int E) {
    int i = blockIdx.x * 256 + threadIdx.x;
    if (i < N) {
        int r = rowptr[i] + bsum[blockIdx.x];
        rowptr[i] = r;
        cursor[i] = r;
    }
    if (i == N) rowptr[N] = E;
}

__global__ void k_place(const int* __restrict__ src, const int* __restrict__ dst,
                        const float* __restrict__ w, const float* __restrict__ dinv,
                        int* cursor, int* __restrict__ col, float* __restrict__ val, int E) {
    int e = blockIdx.x * blockDim.x + threadIdx.x;
    if (e < E) {
        int s = src[e], d = dst[e];
        float nrm = dinv[s] * w[e] * dinv[d];
        int pos = atomicAdd(&cursor[d], 1);
        col[pos] = s;
        val[pos] = nrm;
    }
}

// ---------------- fp32 SGEMM: C[M,N] = A[M,K] @ B[K,N] ----------------
__global__ __launch_bounds__(256) void sgemm(const float* __restrict__ A,
                                             const float* __restrict__ B,
                                             float* __restrict__ C,
                                             int M, int N, int K) {
    __shared__ float As[64][16];   // [row][k]
    __shared__ float Bs[16][64];   // [k][col]
    int col0 = blockIdx.x * 64;
    int row0 = blockIdx.y * 64;
    int tid = threadIdx.x;
    int tx = tid & 15, ty = tid >> 4;
    float acc[4][4] = {};

    for (int k0 = 0; k0 < K; k0 += 16) {
        {   // A tile: 64 rows x 16 k, float4 per thread
            int r = tid >> 2;
            int kk = (tid & 3) * 4;
            int gr = row0 + r;
            float4 a = make_float4(0.f, 0.f, 0.f, 0.f);
            if (gr < M) a = *reinterpret_cast<const float4*>(&A[(size_t)gr * K + k0 + kk]);
            *reinterpret_cast<float4*>(&As[r][kk]) = a;
        }
        {   // B tile: 16 k x 64 cols
            int r = tid >> 4;
            int cc = (tid & 15) * 4;
            float4 b = *reinterpret_cast<const float4*>(&B[(size_t)(k0 + r) * N + col0 + cc]);
            *reinterpret_cast<float4*>(&Bs[r][cc]) = b;
        }
        __syncthreads();
#pragma unroll
        for (int k = 0; k < 16; ++k) {
            float a0 = As[ty * 4 + 0][k];
            float a1 = As[ty * 4 + 1][k];
            float a2 = As[ty * 4 + 2][k];
            float a3 = As[ty * 4 + 3][k];
            float4 b = *reinterpret_cast<const float4*>(&Bs[k][tx * 4]);
            acc[0][0] = fmaf(a0, b.x, acc[0][0]); acc[0][1] = fmaf(a0, b.y, acc[0][1]);
            acc[0][2] = fmaf(a0, b.z, acc[0][2]); acc[0][3] = fmaf(a0, b.w, acc[0][3]);
            acc[1][0] = fmaf(a1, b.x, acc[1][0]); acc[1][1] = fmaf(a1, b.y, acc[1][1]);
            acc[1][2] = fmaf(a1, b.z, acc[1][2]); acc[1][3] = fmaf(a1, b.w, acc[1][3]);
            acc[2][0] = fmaf(a2, b.x, acc[2][0]); acc[2][1] = fmaf(a2, b.y, acc[2][1]);
            acc[2][2] = fmaf(a2, b.z, acc[2][2]); acc[2][3] = fmaf(a2, b.w, acc[2][3]);
            acc[3][0] = fmaf(a3, b.x, acc[3][0]); acc[3][1] = fmaf(a3, b.y, acc[3][1]);
            acc[3][2] = fmaf(a3, b.z, acc[3][2]); acc[3][3] = fmaf(a3, b.w, acc[3][3]);
        }
        __syncthreads();
    }
#pragma unroll
    for (int i = 0; i < 4; ++i) {
        int gr = row0 + ty * 4 + i;
        if (gr < M) {
            float4 o = make_float4(acc[i][0], acc[i][1], acc[i][2], acc[i][3]);
            *reinterpret_cast<float4*>(&C[(size_t)gr * N + col0 + tx * 4]) = o;
        }
    }
}

// ---------------- CSR gather aggregation (+ fused bias / self-loop / relu / dropout) --
template <int F, bool ACT>
__global__ __launch_bounds__(F) void k_aggregate(const float* __restrict__ h,
                                                 const float* __restrict__ dinv,
                                                 const int* __restrict__ rowptr,
                                                 const int* __restrict__ col,
                                                 const float* __restrict__ val,
                                                 const float* __restrict__ bias,
                                                 float* __restrict__ out, int N) {
    int n = blockIdx.x;
    int f = threadIdx.x;
    float di = dinv[n];
    float acc = h[(size_t)n * F + f] * (di * di) + bias[f];  // self-loop + bias
    int p0 = rowptr[n], p1 = rowptr[n + 1];
    for (int p = p0; p < p1; ++p) {
        int c = col[p];
        float v = val[p];
        acc = fmaf(h[(size_t)c * F + f], v, acc);
    }
    if (ACT) {
        acc = fmaxf(acc, 0.f);                       // relu
        unsigned j = (unsigned)(n * F + f);          // flat index into (N, 256)
        acc = dropout_keep(j) ? acc * 2.0f : 0.f;    // p=0.5 => scale 2
    }
    out[(size_t)n * F + f] = acc;
}

// ---------------- launch ----------------
extern "C" void kernel_launch(void* const* d_in, const int* in_sizes, int n_in,
                              void* d_out, int out_size, void* d_ws, size_t ws_size,
                              hipStream_t stream) {
    (void)n_in; (void)out_size; (void)ws_size;
    const float* x  = (const float*)d_in[0];
    const int*   ei = (const int*)d_in[1];
    const float* w  = (const float*)d_in[2];
    const float* W1 = (const float*)d_in[3];
    const float* b1 = (const float*)d_in[4];
    const float* W2 = (const float*)d_in[5];
    const float* b2 = (const float*)d_in[6];
    float* out = (float*)d_out;

    int N = in_sizes[0] / INCH;  // 50000
    int E = in_sizes[1] / 2;     // 800000
    const int* src = ei;
    const int* dst = ei + E;

    char* ws = (char*)d_ws;
    size_t off = 0;
    auto alloc = [&](size_t bytes) -> char* {
        size_t p = (off + 255) & ~(size_t)255;
        off = p + bytes;
        return ws + p;
    };
    float* dinv   = (float*)alloc((size_t)N * 4);            // deg -> dinv in place
    int*   cnt    = (int*)  alloc((size_t)N * 4);            // histogram, then cursor
    int*   rowptr = (int*)  alloc((size_t)(N + 1) * 4);
    int*   bsum   = (int*)  alloc(1024);
    int*   col    = (int*)  alloc((size_t)E * 4);
    float* val    = (float*)alloc((size_t)E * 4);
    float* h1     = (float*)alloc((size_t)N * NHID * 4);     // h1; reused for h2
    float* hd     = (float*)alloc((size_t)N * NHID * 4);     // post relu/dropout

    int nb = (N + 255) / 256;
    int eb = (E + 255) / 256;

    k_init<<<nb, 256, 0, stream>>>(dinv, cnt, N);
    k_edge_deg_hist<<<eb, 256, 0, stream>>>(dst, w, dinv, cnt, E);
    k_dinv<<<nb, 256, 0, stream>>>(dinv, N);
    scan_block<<<nb, 256, 0, stream>>>(cnt, rowptr, bsum, N);
    scan_partials<<<1, 256, 0, stream>>>(bsum, nb);
    scan_add<<<nb, 256, 0, stream>>>(rowptr, cnt /*cursor*/, bsum, N, E);
    k_place<<<eb, 256, 0, stream>>>(src, dst, w, dinv, cnt, col, val, E);

    // layer 1: h1 = x @ W1 ; aggregate + bias + relu + dropout -> hd
    dim3 g1(NHID / 64, (N + 63) / 64);
    sgemm<<<g1, 256, 0, stream>>>(x, W1, h1, N, NHID, INCH);
    k_aggregate<NHID, true><<<N, NHID, 0, stream>>>(h1, dinv, rowptr, col, val, b1, hd, N);

    // layer 2: h2 = hd @ W2 (into h1 buffer) ; aggregate + bias -> out
    dim3 g2(OUTCH / 64, (N + 63) / 64);
    sgemm<<<g2, 256, 0, stream>>>(hd, W2, h1, N, OUTCH, NHID);
    k_aggregate<OUTCH, false><<<N, OUTCH, 0, stream>>>(h1, dinv, rowptr, col, val, b2, out, N);
}

// Round 2
// 463.255 us; speedup vs baseline: 1.2812x; 1.2812x over previous
//
#include <hip/hip_runtime.h>
#include <hip/hip_bf16.h>
#include <cstdint>

#define INCH 128
#define NHID 256
#define OUTCH 128

// ---------------- threefry2x32 (JAX-compatible) ----------------
__device__ __forceinline__ unsigned rotl32(unsigned x, int d) {
    return (x << d) | (x >> (32 - d));
}

__device__ __forceinline__ void threefry2x32(unsigned k0, unsigned k1,
                                             unsigned x0, unsigned x1,
                                             unsigned& o0, unsigned& o1) {
    unsigned ks2 = k0 ^ k1 ^ 0x1BD11BDAu;
#define TF_R(r) { x0 += x1; x1 = rotl32(x1, (r)); x1 ^= x0; }
    x0 += k0; x1 += k1;
    TF_R(13) TF_R(15) TF_R(26) TF_R(6)
    x0 += k1; x1 += ks2 + 1u;
    TF_R(17) TF_R(29) TF_R(16) TF_R(24)
    x0 += ks2; x1 += k0 + 2u;
    TF_R(13) TF_R(15) TF_R(26) TF_R(6)
    x0 += k0; x1 += k1 + 3u;
    TF_R(17) TF_R(29) TF_R(16) TF_R(24)
    x0 += k1; x1 += ks2 + 4u;
    TF_R(13) TF_R(15) TF_R(26) TF_R(6)
    x0 += ks2; x1 += k0 + 5u;
#undef TF_R
    o0 = x0; o1 = x1;
}

// JAX partitionable threefry, 32-bit draw: counter = flat index j (hi=0, lo=j),
// key = (0, 42); bits = o0 ^ o1. uniform<0.5  <=>  MSB(bits)==0.
__device__ __forceinline__ bool dropout_keep(unsigned j) {
    unsigned o0, o1;
    threefry2x32(0u, 42u, 0u, j, o0, o1);
    return ((o0 ^ o1) & 0x80000000u) == 0u;
}

// ---------------- graph preprocessing ----------------
__global__ void k_init(float* deg, int* cnt, int N) {
    int i = blockIdx.x * blockDim.x + threadIdx.x;
    if (i < N) { deg[i] = 1.0f; cnt[i] = 0; }  // self-loop weight 1
}

__global__ void k_edge_deg_hist(const int* __restrict__ dst, const float* __restrict__ w,
                                float* deg, int* cnt, int E) {
    int e = blockIdx.x * blockDim.x + threadIdx.x;
    if (e < E) {
        int d = dst[e];
        atomicAdd(&deg[d], w[e]);
        atomicAdd(&cnt[d], 1);
    }
}

__global__ void k_dinv(float* deg, int N) {
    int i = blockIdx.x * blockDim.x + threadIdx.x;
    if (i < N) {
        float dg = deg[i];
        deg[i] = (dg > 0.f) ? rsqrtf(dg) : 0.f;
    }
}

__global__ void scan_block(const int* __restrict__ cnt, int* __restrict__ rowptr,
                           int* __restrict__ bsum, int N) {
    __shared__ int s[256];
    int t = threadIdx.x;
    int i = blockIdx.x * 256 + t;
    int v = (i < N) ? cnt[i] : 0;
    s[t] = v;
    __syncthreads();
    for (int off = 1; off < 256; off <<= 1) {
        int tv = (t >= off) ? s[t - off] : 0;
        __syncthreads();
        s[t] += tv;
        __syncthreads();
    }
    if (i < N) rowptr[i] = s[t] - v;          // exclusive within block
    if (t == 255) bsum[blockIdx.x] = s[255];  // block total
}

__global__ void scan_partials(int* bsum, int nb) {
    __shared__ int s[256];
    int t = threadIdx.x;
    int v = (t < nb) ? bsum[t] : 0;
    s[t] = v;
    __syncthreads();
    for (int off = 1; off < 256; off <<= 1) {
        int tv = (t >= off) ? s[t - off] : 0;
        __syncthreads();
        s[t] += tv;
        __syncthreads();
    }
    if (t < nb) bsum[t] = s[t] - v;  // exclusive
}

__global__ void scan_add(int* rowptr, int* cursor, const int* __restrict__ bsum,
                         int N, int E) {
    int i = blockIdx.x * 256 + threadIdx.x;
    if (i < N) {
        int r = rowptr[i] + bsum[blockIdx.x];
        rowptr[i] = r;
        cursor[i] = r;
    }
    if (i == N) rowptr[N] = E;
}

__global__ void k_place(const int* __restrict__ src, const int* __restrict__ dst,
                        const float* __restrict__ w, const float* __restrict__ dinv,
                        int* cursor, int* __restrict__ col, float* __restrict__ val, int E) {
    int e = blockIdx.x * blockDim.x + threadIdx.x;
    if (e < E) {
        int s = src[e], d = dst[e];
        float nrm = dinv[s] * w[e] * dinv[d];
        int pos = atomicAdd(&cursor[d], 1);
        col[pos] = s;
        val[pos] = nrm;
    }
}

// ---------------- fp32 SGEMM: C[M,N] = A[M,K] @ B[K,N] (+bias,+relu+dropout) ------
// ACT: C = dropout(relu(AB + bias)), dropout index j = row*N + col (key 42, p=0.5).
template <bool ACT>
__global__ __launch_bounds__(256) void sgemm_ep(const float* __restrict__ A,
                                                const float* __restrict__ B,
                                                const float* __restrict__ bias,
                                                float* __restrict__ C,
                                                int M, int N, int K) {
    __shared__ float As[64][16];   // [row][k]
    __shared__ float Bs[16][64];   // [k][col]
    int col0 = blockIdx.x * 64;
    int row0 = blockIdx.y * 64;
    int tid = threadIdx.x;
    int tx = tid & 15, ty = tid >> 4;
    float acc[4][4] = {};

    for (int k0 = 0; k0 < K; k0 += 16) {
        {   // A tile: 64 rows x 16 k, float4 per thread
            int r = tid >> 2;
            int kk = (tid & 3) * 4;
            int gr = row0 + r;
            float4 a = make_float4(0.f, 0.f, 0.f, 0.f);
            if (gr < M) a = *reinterpret_cast<const float4*>(&A[(size_t)gr * K + k0 + kk]);
            *reinterpret_cast<float4*>(&As[r][kk]) = a;
        }
        {   // B tile: 16 k x 64 cols
            int r = tid >> 4;
            int cc = (tid & 15) * 4;
            float4 b = *reinterpret_cast<const float4*>(&B[(size_t)(k0 + r) * N + col0 + cc]);
            *reinterpret_cast<float4*>(&Bs[r][cc]) = b;
        }
        __syncthreads();
#pragma unroll
        for (int k = 0; k < 16; ++k) {
            float a0 = As[ty * 4 + 0][k];
            float a1 = As[ty * 4 + 1][k];
            float a2 = As[ty * 4 + 2][k];
            float a3 = As[ty * 4 + 3][k];
            float4 b = *reinterpret_cast<const float4*>(&Bs[k][tx * 4]);
            acc[0][0] = fmaf(a0, b.x, acc[0][0]); acc[0][1] = fmaf(a0, b.y, acc[0][1]);
            acc[0][2] = fmaf(a0, b.z, acc[0][2]); acc[0][3] = fmaf(a0, b.w, acc[0][3]);
            acc[1][0] = fmaf(a1, b.x, acc[1][0]); acc[1][1] = fmaf(a1, b.y, acc[1][1]);
            acc[1][2] = fmaf(a1, b.z, acc[1][2]); acc[1][3] = fmaf(a1, b.w, acc[1][3]);
            acc[2][0] = fmaf(a2, b.x, acc[2][0]); acc[2][1] = fmaf(a2, b.y, acc[2][1]);
            acc[2][2] = fmaf(a2, b.z, acc[2][2]); acc[2][3] = fmaf(a2, b.w, acc[2][3]);
            acc[3][0] = fmaf(a3, b.x, acc[3][0]); acc[3][1] = fmaf(a3, b.y, acc[3][1]);
            acc[3][2] = fmaf(a3, b.z, acc[3][2]); acc[3][3] = fmaf(a3, b.w, acc[3][3]);
        }
        __syncthreads();
    }
#pragma unroll
    for (int i = 0; i < 4; ++i) {
        int gr = row0 + ty * 4 + i;
        if (gr < M) {
            int gc = col0 + tx * 4;
            float4 o = make_float4(acc[i][0], acc[i][1], acc[i][2], acc[i][3]);
            if (ACT) {
                float bx = bias[gc], by = bias[gc + 1], bz = bias[gc + 2], bw = bias[gc + 3];
                o.x = fmaxf(o.x + bx, 0.f); o.y = fmaxf(o.y + by, 0.f);
                o.z = fmaxf(o.z + bz, 0.f); o.w = fmaxf(o.w + bw, 0.f);
                unsigned j = (unsigned)gr * (unsigned)N + (unsigned)gc;
                o.x = dropout_keep(j + 0u) ? o.x * 2.f : 0.f;
                o.y = dropout_keep(j + 1u) ? o.y * 2.f : 0.f;
                o.z = dropout_keep(j + 2u) ? o.z * 2.f : 0.f;
                o.w = dropout_keep(j + 3u) ? o.w * 2.f : 0.f;
            }
            *reinterpret_cast<float4*>(&C[(size_t)gr * N + gc]) = o;
        }
    }
}

// ------------- CSR gather aggregation, F=128, float4 lanes -------------------
// out[n] = bias + dinv[n]^2 * h[n] + sum_{p in row n} val[p] * h[col[p]]
// 32 lanes per node (float4 each), 8 nodes per 256-thread block.
__global__ __launch_bounds__(256) void k_aggregate4(const float4* __restrict__ h4,
                                                    const float* __restrict__ dinv,
                                                    const int* __restrict__ rowptr,
                                                    const int* __restrict__ col,
                                                    const float* __restrict__ val,
                                                    const float* __restrict__ bias,  // may be null
                                                    float4* __restrict__ out4, int N) {
    int node = blockIdx.x * 8 + (threadIdx.x >> 5);
    int lane = threadIdx.x & 31;
    if (node >= N) return;
    float di = dinv[node];
    float s = di * di;
    float4 self = h4[(size_t)node * 32 + lane];
    float4 acc;
    acc.x = self.x * s; acc.y = self.y * s; acc.z = self.z * s; acc.w = self.w * s;
    if (bias) {
        float4 b = reinterpret_cast<const float4*>(bias)[lane];
        acc.x += b.x; acc.y += b.y; acc.z += b.z; acc.w += b.w;
    }
    int p0 = rowptr[node], p1 = rowptr[node + 1];
    int p = p0;
    for (; p + 4 <= p1; p += 4) {
        int c0 = col[p], c1 = col[p + 1], c2 = col[p + 2], c3 = col[p + 3];
        float v0 = val[p], v1 = val[p + 1], v2 = val[p + 2], v3 = val[p + 3];
        float4 g0 = h4[(size_t)c0 * 32 + lane];
        float4 g1 = h4[(size_t)c1 * 32 + lane];
        float4 g2 = h4[(size_t)c2 * 32 + lane];
        float4 g3 = h4[(size_t)c3 * 32 + lane];
        acc.x = fmaf(g0.x, v0, acc.x); acc.y = fmaf(g0.y, v0, acc.y);
        acc.z = fmaf(g0.z, v0, acc.z); acc.w = fmaf(g0.w, v0, acc.w);
        acc.x = fmaf(g1.x, v1, acc.x); acc.y = fmaf(g1.y, v1, acc.y);
        acc.z = fmaf(g1.z, v1, acc.z); acc.w = fmaf(g1.w, v1, acc.w);
        acc.x = fmaf(g2.x, v2, acc.x); acc.y = fmaf(g2.y, v2, acc.y);
        acc.z = fmaf(g2.z, v2, acc.z); acc.w = fmaf(g2.w, v2, acc.w);
        acc.x = fmaf(g3.x, v3, acc.x); acc.y = fmaf(g3.y, v3, acc.y);
        acc.z = fmaf(g3.z, v3, acc.z); acc.w = fmaf(g3.w, v3, acc.w);
    }
    for (; p < p1; ++p) {
        int c = col[p];
        float v = val[p];
        float4 g = h4[(size_t)c * 32 + lane];
        acc.x = fmaf(g.x, v, acc.x); acc.y = fmaf(g.y, v, acc.y);
        acc.z = fmaf(g.z, v, acc.z); acc.w = fmaf(g.w, v, acc.w);
    }
    out4[(size_t)node * 32 + lane] = acc;
}

// ---------------- launch ----------------
extern "C" void kernel_launch(void* const* d_in, const int* in_sizes, int n_in,
                              void* d_out, int out_size, void* d_ws, size_t ws_size,
                              hipStream_t stream) {
    (void)n_in; (void)out_size; (void)ws_size;
    const float* x  = (const float*)d_in[0];
    const int*   ei = (const int*)d_in[1];
    const float* w  = (const float*)d_in[2];
    const float* W1 = (const float*)d_in[3];
    const float* b1 = (const float*)d_in[4];
    const float* W2 = (const float*)d_in[5];
    const float* b2 = (const float*)d_in[6];
    float* out = (float*)d_out;

    int N = in_sizes[0] / INCH;  // 50000
    int E = in_sizes[1] / 2;     // 800000
    const int* src = ei;
    const int* dst = ei + E;

    char* ws = (char*)d_ws;
    size_t off = 0;
    auto alloc = [&](size_t bytes) -> char* {
        size_t p = (off + 255) & ~(size_t)255;
        off = p + bytes;
        return ws + p;
    };
    float* dinv   = (float*)alloc((size_t)N * 4);            // deg -> dinv in place
    int*   cnt    = (int*)  alloc((size_t)N * 4);            // histogram, then cursor
    int*   rowptr = (int*)  alloc((size_t)(N + 1) * 4);
    int*   bsum   = (int*)  alloc(1024);
    int*   col    = (int*)  alloc((size_t)E * 4);
    float* val    = (float*)alloc((size_t)E * 4);
    float* ax     = (float*)alloc((size_t)N * INCH * 4);     // A@x           (N x 128)
    float* hd     = (float*)alloc((size_t)N * NHID * 4);     // relu/dropout  (N x 256)
    float* g2     = (float*)alloc((size_t)N * OUTCH * 4);    // hd @ W2       (N x 128)

    int nb = (N + 255) / 256;
    int eb = (E + 255) / 256;

    k_init<<<nb, 256, 0, stream>>>(dinv, cnt, N);
    k_edge_deg_hist<<<eb, 256, 0, stream>>>(dst, w, dinv, cnt, E);
    k_dinv<<<nb, 256, 0, stream>>>(dinv, N);
    scan_block<<<nb, 256, 0, stream>>>(cnt, rowptr, bsum, N);
    scan_partials<<<1, 256, 0, stream>>>(bsum, nb);
    scan_add<<<nb, 256, 0, stream>>>(rowptr, cnt /*cursor*/, bsum, N, E);
    k_place<<<eb, 256, 0, stream>>>(src, dst, w, dinv, cnt, col, val, E);

    int ab = (N + 7) / 8;  // 8 nodes per block

    // layer 1: ax = A @ x (F=128); hd = dropout(relu(ax @ W1 + b1))
    k_aggregate4<<<ab, 256, 0, stream>>>((const float4*)x, dinv, rowptr, col, val,
                                         nullptr, (float4*)ax, N);
    dim3 gg1(NHID / 64, (N + 63) / 64);
    sgemm_ep<true><<<gg1, 256, 0, stream>>>(ax, W1, b1, hd, N, NHID, INCH);

    // layer 2: g2 = hd @ W2 ; out = A @ g2 + b2 (F=128)
    dim3 gg2(OUTCH / 64, (N + 63) / 64);
    sgemm_ep<false><<<gg2, 256, 0, stream>>>(hd, W2, nullptr, g2, N, OUTCH, NHID);
    k_aggregate4<<<ab, 256, 0, stream>>>((const float4*)g2, dinv, rowptr, col, val,
                                         b2, (float4*)out, N);
}